// Round 1
// baseline (113.392 us; speedup 1.0000x reference)
//
#include <hip/hip_runtime.h>

#define NROW 8192
#define DIM  256
#define INV_T 5.0f
#define BM 128
#define BN 128
#define CSPLIT 8
#define COLS_PER_BLOCK (NROW / CSPLIT)   // 1024
#define NT (COLS_PER_BLOCK / BN)         // 8 column tiles per block
#define TOTAL_STEPS (NT * (DIM / 32))    // 64 (tile, kstep) pairs

typedef _Float16 f16x8 __attribute__((ext_vector_type(8)));
typedef _Float16 f16x4 __attribute__((ext_vector_type(4)));
typedef float    f32x4 __attribute__((ext_vector_type(4)));

__device__ __forceinline__ void gload_lds16(const void* g, void* l) {
  __builtin_amdgcn_global_load_lds(
      (__attribute__((address_space(1))) void*)(g),
      (__attribute__((address_space(3))) void*)(l),
      16, 0, 0);
}

// ---------------- normalize rows + convert to fp16 ----------------
__global__ __launch_bounds__(256) void norm_kernel(
    const float* __restrict__ zv, const float* __restrict__ zf,
    _Float16* __restrict__ ov, _Float16* __restrict__ of) {
  const float* in  = blockIdx.y ? zf : zv;
  _Float16*    out = blockIdx.y ? of : ov;
  int row  = blockIdx.x * 4 + (threadIdx.x >> 6);
  int lane = threadIdx.x & 63;
  float4 v = ((const float4*)(in + (size_t)row * DIM))[lane];
  float ss = v.x * v.x + v.y * v.y + v.z * v.z + v.w * v.w;
#pragma unroll
  for (int off = 1; off < 64; off <<= 1) ss += __shfl_xor(ss, off);
  float inv = 1.0f / fmaxf(sqrtf(ss), 1e-12f);
  f16x4 o;
  o.x = (_Float16)(v.x * inv);
  o.y = (_Float16)(v.y * inv);
  o.z = (_Float16)(v.z * inv);
  o.w = (_Float16)(v.w * inv);
  ((f16x4*)(out + (size_t)row * DIM))[lane] = o;
}

// ---------------- fused GEMM + masked exp/row-reductions ----------------
// grid (NROW/BM = 64, CSPLIT = 8), 256 threads (4 waves, 2x2).
// Each block: rows [row0, row0+128), cols [col0, col0+1024) in 8 tiles of 128.
// Per-lane S/P/C partials persist across tiles; written (deterministically,
// no atomics) to per-(split,wc) slots in workspace.
__global__ __launch_bounds__(256, 2) void fused_kernel(
    const _Float16* __restrict__ zv, const _Float16* __restrict__ zf,
    const float* __restrict__ Gf,
    float* __restrict__ Sp, float* __restrict__ Pp, float* __restrict__ Cp) {

  __shared__ __align__(16) _Float16 Asf[BM * DIM];      // 64 KB, XOR-swizzled
  __shared__ __align__(16) _Float16 Bs[2][BN * 32];     // 2 x 8 KB, XOR-swizzled

  const int t    = threadIdx.x;
  const int lane = t & 63;
  const int w    = t >> 6;
  const int wr   = w >> 1;        // wave row quadrant (0..1)
  const int wc   = w & 1;         // wave col quadrant (0..1)
  const int l15  = lane & 15;
  const int kq   = lane >> 4;     // 0..3
  const int row0 = blockIdx.x * BM;
  const int col0 = blockIdx.y * COLS_PER_BLOCK;

  // ---- stage full A tile (128 x 256 fp16), source pre-swizzled ----
  // linear 16B chunk i = c*256 + t : row = i>>5, physical chunk cbP = i&31,
  // logical chunk cbL = cbP ^ (row&7)  (involution)
#pragma unroll
  for (int c = 0; c < 16; ++c) {
    int i = c * 256 + t;
    int row = i >> 5, cbP = i & 31;
    int cbL = cbP ^ (row & 7);
    gload_lds16(zv + (size_t)(row0 + row) * DIM + cbL * 8,
                &Asf[(size_t)(c * 256 + w * 64) * 8]);
  }

  // ---- stage B for step s into buf: tile tt=s>>3 (cols), kstep kk=s&7 ----
  auto stageB = [&](int buf, int s) {
    int tt = s >> 3, kk = s & 7;
    int ct0 = col0 + tt * BN;
    int k0 = kk * 32;
#pragma unroll
    for (int c = 0; c < 2; ++c) {
      int i = c * 256 + t;
      int row = i >> 2, cbP = i & 3;
      int cbL = cbP ^ ((row >> 1) & 3);
      gload_lds16(zf + (size_t)(ct0 + row) * DIM + k0 + cbL * 8,
                  &Bs[buf][(size_t)(c * 256 + w * 64) * 8]);
    }
  };

  stageB(0, 0);
  asm volatile("s_waitcnt vmcnt(0)" ::: "memory");
  __syncthreads();

  f32x4 acc[4][4];
  float Sa[16], Pa[16], Ca[16];
#pragma unroll
  for (int i = 0; i < 16; ++i) { Sa[i] = 0.0f; Pa[i] = 0.0f; Ca[i] = 0.0f; }

#pragma unroll 2
  for (int s = 0; s < TOTAL_STEPS; ++s) {
    const int cur = s & 1;
    if ((s & 7) == 0) {
#pragma unroll
      for (int m = 0; m < 4; ++m)
#pragma unroll
        for (int n = 0; n < 4; ++n) acc[m][n] = (f32x4)(0.0f);
    }
    if (s < TOTAL_STEPS - 1) stageB(cur ^ 1, s + 1);

    const int k0 = (s & 7) * 32;
    f16x8 af[4], bf[4];
#pragma unroll
    for (int m = 0; m < 4; ++m) {
      int row = wr * 64 + m * 16 + l15;
      int cbL = (k0 >> 3) + kq;
      int cbP = cbL ^ (row & 7);
      af[m] = *(const f16x8*)&Asf[(size_t)row * 256 + cbP * 8];
    }
#pragma unroll
    for (int n = 0; n < 4; ++n) {
      int row = wc * 64 + n * 16 + l15;
      int cbP = kq ^ ((row >> 1) & 3);
      bf[n] = *(const f16x8*)&Bs[cur][(size_t)row * 32 + cbP * 8];
    }
#pragma unroll
    for (int m = 0; m < 4; ++m)
#pragma unroll
      for (int n = 0; n < 4; ++n)
        acc[m][n] = __builtin_amdgcn_mfma_f32_16x16x32_f16(af[m], bf[n], acc[m][n], 0, 0, 0);

    if ((s & 7) == 7) {   // tile epilogue: consume acc into S/P/C partials
      int tt = s >> 3;
      int ct0 = col0 + tt * BN;
#pragma unroll
      for (int m = 0; m < 4; ++m) {
        int gi = row0 + wr * 64 + m * 16 + kq * 4;    // rows gi..gi+3 (reg r)
#pragma unroll
        for (int n = 0; n < 4; ++n) {
          int gj = ct0 + wc * 64 + n * 16 + l15;
          const float* gp = Gf + (size_t)gi * NROW + gj;
#pragma unroll
          for (int r = 0; r < 4; ++r) {
            float sim = acc[m][n][r] * INV_T;
            float g = gp[(size_t)r * NROW];
            bool pos = (g > 0.0f) || ((gi + r) == gj);
            float e = __expf(sim);
            int idx = m * 4 + r;
            Sa[idx] += pos ? 1.0f : e;     // pos slot contributes exp(0)=1
            Pa[idx] += pos ? sim : 0.0f;
            Ca[idx] += pos ? 1.0f : 0.0f;
          }
        }
      }
    }
    asm volatile("s_waitcnt vmcnt(0)" ::: "memory");
    __syncthreads();
  }

  // ---- reduce across the 16 column-lanes of each row group ----
#pragma unroll
  for (int off = 1; off <= 8; off <<= 1) {
#pragma unroll
    for (int i = 0; i < 16; ++i) {
      Sa[i] += __shfl_xor(Sa[i], off);
      Pa[i] += __shfl_xor(Pa[i], off);
      Ca[i] += __shfl_xor(Ca[i], off);
    }
  }
  const int slot = blockIdx.y * 2 + wc;   // 16 slots total
#pragma unroll
  for (int i = 0; i < 16; ++i) {          // static indices (no scratch spill)
    if (l15 == i) {
      int m = i >> 2, r = i & 3;
      int row = row0 + wr * 64 + m * 16 + kq * 4 + r;
      Sp[(size_t)slot * NROW + row] = Sa[i];
      Pp[(size_t)slot * NROW + row] = Pa[i];
      Cp[(size_t)slot * NROW + row] = Ca[i];
    }
  }
}

// ---------------- per-row loss + block partials (deterministic) ----------------
__global__ __launch_bounds__(256) void loss_partial_kernel(
    const float* __restrict__ Sp, const float* __restrict__ Pp,
    const float* __restrict__ Cp, float* __restrict__ bsum) {
  int row = blockIdx.x * 256 + threadIdx.x;
  float S = 0.0f, P = 0.0f, C = 0.0f;
#pragma unroll
  for (int s2 = 0; s2 < 16; ++s2) {
    S += Sp[(size_t)s2 * NROW + row];
    P += Pp[(size_t)s2 * NROW + row];
    C += Cp[(size_t)s2 * NROW + row];
  }
  float pos = P / (C + 1e-8f);
  float contrib = __logf(S + __expf(pos)) - pos;
#pragma unroll
  for (int off = 1; off < 64; off <<= 1) contrib += __shfl_xor(contrib, off);
  __shared__ float wsum[4];
  if ((threadIdx.x & 63) == 0) wsum[threadIdx.x >> 6] = contrib;
  __syncthreads();
  if (threadIdx.x == 0) bsum[blockIdx.x] = wsum[0] + wsum[1] + wsum[2] + wsum[3];
}

__global__ void loss_final_kernel(const float* __restrict__ bsum, float* __restrict__ out) {
  int lane = threadIdx.x;
  float v = (lane < 32) ? bsum[lane] : 0.0f;
#pragma unroll
  for (int off = 1; off < 64; off <<= 1) v += __shfl_xor(v, off);
  if (lane == 0) out[0] = v / (float)NROW;
}

extern "C" void kernel_launch(void* const* d_in, const int* in_sizes, int n_in,
                              void* d_out, int out_size, void* d_ws, size_t ws_size,
                              hipStream_t stream) {
  const float* zv = (const float*)d_in[0];
  const float* zf = (const float*)d_in[1];
  const float* Gf = (const float*)d_in[2];
  float* out = (float*)d_out;

  char* ws = (char*)d_ws;
  _Float16* zv16 = (_Float16*)ws;                          // 4 MB
  _Float16* zf16 = zv16 + (size_t)NROW * DIM;              // 4 MB
  float* Sp = (float*)(ws + 2 * (size_t)NROW * DIM * sizeof(_Float16));
  float* Pp = Sp + 16 * (size_t)NROW;
  float* Cp = Pp + 16 * (size_t)NROW;
  float* bsum = Cp + 16 * (size_t)NROW;                    // 32 floats

  norm_kernel<<<dim3(NROW / 4, 2), 256, 0, stream>>>(zv, zf, zv16, zf16);
  fused_kernel<<<dim3(NROW / BM, CSPLIT), 256, 0, stream>>>(zv16, zf16, Gf, Sp, Pp, Cp);
  loss_partial_kernel<<<NROW / 256, 256, 0, stream>>>(Sp, Pp, Cp, bsum);
  loss_final_kernel<<<1, 64, 0, stream>>>(bsum, out);
}

// Round 2
// 102.639 us; speedup vs baseline: 1.1048x; 1.1048x over previous
//
#include <hip/hip_runtime.h>

#define NROW 8192
#define DIM  256
#define INV_T 5.0f
#define BM 128
#define BN 128
#define CSPLIT 8
#define COLS_PER_BLOCK (NROW / CSPLIT)   // 1024
#define NT 8                              // column tiles per block

typedef _Float16 f16x8 __attribute__((ext_vector_type(8)));
typedef _Float16 f16x4 __attribute__((ext_vector_type(4)));
typedef float    f32x4 __attribute__((ext_vector_type(4)));
typedef unsigned long long u64;

__device__ __forceinline__ void gload_lds16(const void* g, void* l) {
  __builtin_amdgcn_global_load_lds(
      (__attribute__((address_space(1))) void*)(g),
      (__attribute__((address_space(3))) void*)(l),
      16, 0, 0);
}

// ---------------- normalize rows + convert to fp16 ----------------
__global__ __launch_bounds__(256) void norm_kernel(
    const float* __restrict__ zv, const float* __restrict__ zf,
    _Float16* __restrict__ ov, _Float16* __restrict__ of) {
  const float* in  = blockIdx.y ? zf : zv;
  _Float16*    out = blockIdx.y ? of : ov;
  int row  = blockIdx.x * 4 + (threadIdx.x >> 6);
  int lane = threadIdx.x & 63;
  float4 v = ((const float4*)(in + (size_t)row * DIM))[lane];
  float ss = v.x * v.x + v.y * v.y + v.z * v.z + v.w * v.w;
#pragma unroll
  for (int off = 1; off < 64; off <<= 1) ss += __shfl_xor(ss, off);
  float inv = 1.0f / fmaxf(sqrtf(ss), 1e-12f);
  f16x4 o;
  o.x = (_Float16)(v.x * inv);
  o.y = (_Float16)(v.y * inv);
  o.z = (_Float16)(v.z * inv);
  o.w = (_Float16)(v.w * inv);
  ((f16x4*)(out + (size_t)row * DIM))[lane] = o;
}

// ---------------- fused GEMM + ballot-packed mask + exp/row-reductions ----------------
__global__ __launch_bounds__(256, 2) void fused_kernel(
    const _Float16* __restrict__ zv, const _Float16* __restrict__ zf,
    const float* __restrict__ Gf,
    float* __restrict__ Sp, float* __restrict__ Pp, float* __restrict__ Cp) {

  __shared__ __align__(16) _Float16 Asf[BM * DIM];      // 64 KB, XOR-swizzled
  __shared__ __align__(16) _Float16 Bs[2][BN * 32];     // 2 x 8 KB, XOR-swizzled

  const int t_   = threadIdx.x;
  const int lane = t_ & 63;
  const int w    = t_ >> 6;
  const int wr   = w >> 1;
  const int wc   = w & 1;
  const int l15  = lane & 15;
  const int kq   = lane >> 4;
  const int row0 = blockIdx.x * BM;
  const int col0 = blockIdx.y * COLS_PER_BLOCK;

  // ---- stage full A tile (128 x 256 fp16), source pre-swizzled ----
#pragma unroll
  for (int c = 0; c < 16; ++c) {
    int i = c * 256 + t_;
    int row = i >> 5, cbP = i & 31;
    int cbL = cbP ^ (row & 7);
    gload_lds16(zv + (size_t)(row0 + row) * DIM + cbL * 8,
                &Asf[(size_t)(c * 256 + w * 64) * 8]);
  }

  auto stageB = [&](int buf, int s) {
    int tt = s >> 3, kk = s & 7;
    int ct0 = col0 + tt * BN;
    int k0 = kk * 32;
#pragma unroll
    for (int c = 0; c < 2; ++c) {
      int i = c * 256 + t_;
      int row = i >> 2, cbP = i & 3;
      int cbL = cbP ^ ((row >> 1) & 3);
      gload_lds16(zf + (size_t)(ct0 + row) * DIM + k0 + cbL * 8,
                  &Bs[buf][(size_t)(c * 256 + w * 64) * 8]);
    }
  };

  // Gf staging: wave (wr,wc) owns the 64x64 sub-tile rows [wr*64,+64) x cols [wc*64,+64).
  // chunk c (0..15) = rows 4c..4c+3; lane reads float4 at (row 4c+(lane>>4), col l15*4).
  auto issueGf = [&](float4* q, int tt, int c0) {
    const float* base = Gf + (size_t)(row0 + wr * 64 + (lane >> 4)) * NROW
                           + col0 + tt * BN + wc * 64 + l15 * 4;
#pragma unroll
    for (int j = 0; j < 4; ++j)
      q[j] = *(const float4*)(base + (size_t)((c0 + j) * 4) * NROW);
  };

  // Ballot-pack 4 chunks (a 16-row group = one m block) into this lane's mask word.
  // Consumer bit for (m,n,r) is bit (r*16 + n*4) of wm[m].
  auto maskFrom4 = [&](const float4* q) -> u64 {
    u64 e = 0;
#pragma unroll
    for (int j = 0; j < 4; ++j) {
      u64 b0 = __ballot(q[j].x > 0.0f);
      u64 b1 = __ballot(q[j].y > 0.0f);
      u64 b2 = __ballot(q[j].z > 0.0f);
      u64 b3 = __ballot(q[j].w > 0.0f);
      u64 s01 = (l15 & 1) ? b1 : b0;
      u64 s23 = (l15 & 1) ? b3 : b2;
      u64 bsel = (l15 & 2) ? s23 : s01;
      u64 ej = bsel >> (l15 >> 2);
      e = (kq == j) ? ej : e;
    }
    return e;
  };

  stageB(0, 0);

  // ---- prologue: build mask for tile 0 ----
  u64 wm[4];
  {
    float4 gp[8];
#pragma unroll
    for (int c = 0; c < 8; ++c) issueGf(gp + c, 0, c);   // chunks 0..7 (1 each)
    wm[0] = maskFrom4(gp);
    wm[1] = maskFrom4(gp + 4);
#pragma unroll
    for (int c = 0; c < 8; ++c) issueGf(gp + c, 0, 8 + c);
    wm[2] = maskFrom4(gp);
    wm[3] = maskFrom4(gp + 4);
  }
  asm volatile("s_waitcnt vmcnt(0)" ::: "memory");
  __builtin_amdgcn_s_barrier();

  f32x4 acc[4][4];
  float Sa[16], Pa[16], Ca[16];
  u64 wn[4];
  float4 gvA[4], gvB[4];
#pragma unroll
  for (int i = 0; i < 16; ++i) { Sa[i] = 0.0f; Pa[i] = 0.0f; Ca[i] = 0.0f; }

#define STEP(KK)                                                               \
  do {                                                                         \
    if ((KK) == 0) {                                                           \
      _Pragma("unroll") for (int m = 0; m < 4; ++m)                            \
          _Pragma("unroll") for (int n = 0; n < 4; ++n)                        \
              acc[m][n] = (f32x4)(0.0f);                                       \
    }                                                                          \
    f16x8 af[4], bf[4];                                                        \
    _Pragma("unroll") for (int m = 0; m < 4; ++m) {                            \
      int row = wr * 64 + m * 16 + l15;                                        \
      int cbL = ((KK) * 32 >> 3) + kq;                                         \
      int cbP = cbL ^ (row & 7);                                               \
      af[m] = *(const f16x8*)&Asf[(size_t)row * 256 + cbP * 8];                \
    }                                                                          \
    _Pragma("unroll") for (int n = 0; n < 4; ++n) {                            \
      int row = wc * 64 + n * 16 + l15;                                        \
      int cbP = kq ^ ((row >> 1) & 3);                                         \
      bf[n] = *(const f16x8*)&Bs[(KK) & 1][(size_t)row * 32 + cbP * 8];        \
    }                                                                          \
    if (t < NT - 1 || (KK) < 7) stageB(((KK) + 1) & 1, t * 8 + (KK) + 1);      \
    asm volatile("" ::: "memory");                                             \
    if ((KK) < 4) {                                                            \
      if (t < NT - 1) issueGf(((KK) & 1) ? gvB : gvA, t + 1, (KK) * 4);        \
    }                                                                          \
    asm volatile("" ::: "memory");                                             \
    _Pragma("unroll") for (int m = 0; m < 4; ++m)                              \
        _Pragma("unroll") for (int n = 0; n < 4; ++n)                          \
            acc[m][n] = __builtin_amdgcn_mfma_f32_16x16x32_f16(                \
                af[m], bf[n], acc[m][n], 0, 0, 0);                             \
    if ((KK) >= 1 && (KK) <= 4) {                                              \
      if (t < NT - 1) wn[(KK) - 1] = maskFrom4(((KK) & 1) ? gvA : gvB);        \
    }                                                                          \
    if ((KK) == 7) {                                                           \
      int ct0 = col0 + t * BN;                                                 \
      _Pragma("unroll") for (int m = 0; m < 4; ++m) {                          \
        int gi = row0 + wr * 64 + m * 16 + kq * 4;                             \
        _Pragma("unroll") for (int n = 0; n < 4; ++n) {                        \
          int gj = ct0 + wc * 64 + n * 16 + l15;                               \
          _Pragma("unroll") for (int r = 0; r < 4; ++r) {                      \
            float sim = acc[m][n][r] * INV_T;                                  \
            bool pos = (((unsigned)(wm[m] >> (r * 16 + n * 4)) & 1u) != 0u) || \
                       ((gi + r) == gj);                                       \
            float e = __expf(sim);                                             \
            int idx = m * 4 + r;                                               \
            Sa[idx] += pos ? 1.0f : e;                                         \
            Pa[idx] += pos ? sim : 0.0f;                                       \
            Ca[idx] += pos ? 1.0f : 0.0f;                                      \
          }                                                                    \
        }                                                                      \
      }                                                                        \
      if (t < NT - 1) {                                                        \
        _Pragma("unroll") for (int i = 0; i < 4; ++i) wm[i] = wn[i];           \
      }                                                                        \
    }                                                                          \
    if ((KK) < 4) {                                                            \
      if (t < NT - 1)                                                          \
        asm volatile("s_waitcnt vmcnt(4)" ::: "memory");                       \
      else                                                                     \
        asm volatile("s_waitcnt vmcnt(0)" ::: "memory");                       \
    } else {                                                                   \
      asm volatile("s_waitcnt vmcnt(0)" ::: "memory");                         \
    }                                                                          \
    __builtin_amdgcn_s_barrier();                                              \
  } while (0)

#pragma unroll 1
  for (int t = 0; t < NT; ++t) {
    STEP(0); STEP(1); STEP(2); STEP(3);
    STEP(4); STEP(5); STEP(6); STEP(7);
  }
#undef STEP

  // ---- reduce across the 16 column-lanes of each row group ----
#pragma unroll
  for (int off = 1; off <= 8; off <<= 1) {
#pragma unroll
    for (int i = 0; i < 16; ++i) {
      Sa[i] += __shfl_xor(Sa[i], off);
      Pa[i] += __shfl_xor(Pa[i], off);
      Ca[i] += __shfl_xor(Ca[i], off);
    }
  }
  const int slot = blockIdx.y * 2 + wc;
#pragma unroll
  for (int i = 0; i < 16; ++i) {
    if (l15 == i) {
      int m = i >> 2, r = i & 3;
      int row = row0 + wr * 64 + m * 16 + kq * 4 + r;
      Sp[(size_t)slot * NROW + row] = Sa[i];
      Pp[(size_t)slot * NROW + row] = Pa[i];
      Cp[(size_t)slot * NROW + row] = Ca[i];
    }
  }
}

// ---------------- per-row loss + block partials (deterministic) ----------------
__global__ __launch_bounds__(256) void loss_partial_kernel(
    const float* __restrict__ Sp, const float* __restrict__ Pp,
    const float* __restrict__ Cp, float* __restrict__ bsum) {
  int row = blockIdx.x * 256 + threadIdx.x;
  float S = 0.0f, P = 0.0f, C = 0.0f;
#pragma unroll
  for (int s2 = 0; s2 < 16; ++s2) {
    S += Sp[(size_t)s2 * NROW + row];
    P += Pp[(size_t)s2 * NROW + row];
    C += Cp[(size_t)s2 * NROW + row];
  }
  float pos = P / (C + 1e-8f);
  float contrib = __logf(S + __expf(pos)) - pos;
#pragma unroll
  for (int off = 1; off < 64; off <<= 1) contrib += __shfl_xor(contrib, off);
  __shared__ float wsum[4];
  if ((threadIdx.x & 63) == 0) wsum[threadIdx.x >> 6] = contrib;
  __syncthreads();
  if (threadIdx.x == 0) bsum[blockIdx.x] = wsum[0] + wsum[1] + wsum[2] + wsum[3];
}

__global__ void loss_final_kernel(const float* __restrict__ bsum, float* __restrict__ out) {
  int lane = threadIdx.x;
  float v = (lane < 32) ? bsum[lane] : 0.0f;
#pragma unroll
  for (int off = 1; off < 64; off <<= 1) v += __shfl_xor(v, off);
  if (lane == 0) out[0] = v / (float)NROW;
}

extern "C" void kernel_launch(void* const* d_in, const int* in_sizes, int n_in,
                              void* d_out, int out_size, void* d_ws, size_t ws_size,
                              hipStream_t stream) {
  const float* zv = (const float*)d_in[0];
  const float* zf = (const float*)d_in[1];
  const float* Gf = (const float*)d_in[2];
  float* out = (float*)d_out;

  char* ws = (char*)d_ws;
  _Float16* zv16 = (_Float16*)ws;
  _Float16* zf16 = zv16 + (size_t)NROW * DIM;
  float* Sp = (float*)(ws + 2 * (size_t)NROW * DIM * sizeof(_Float16));
  float* Pp = Sp + 16 * (size_t)NROW;
  float* Cp = Pp + 16 * (size_t)NROW;
  float* bsum = Cp + 16 * (size_t)NROW;

  norm_kernel<<<dim3(NROW / 4, 2), 256, 0, stream>>>(zv, zf, zv16, zf16);
  fused_kernel<<<dim3(NROW / BM, CSPLIT), 256, 0, stream>>>(zv16, zf16, Gf, Sp, Pp, Cp);
  loss_partial_kernel<<<NROW / 256, 256, 0, stream>>>(Sp, Pp, Cp, bsum);
  loss_final_kernel<<<1, 64, 0, stream>>>(bsum, out);
}